// Round 1
// baseline (27.138 us; speedup 1.0000x reference)
//
#include <hip/hip_runtime.h>

#define BB 32
#define PP 2048
#define GG 128

__global__ __launch_bounds__(256) void MaxExtractor_kernel(
    const float4* __restrict__ pred_boxes,   // [B*P] as float4
    const float*  __restrict__ pred_scores,  // [B*P]
    const int*    __restrict__ pred_classes, // [B*P]
    const float4* __restrict__ gt_boxes,     // [B*G] as float4
    float*        __restrict__ out)          // [2*B]: [0..B)=max_prob, [B..2B)=max_iou
{
    __shared__ float4 sgt[GG];
    __shared__ float  sag[GG];

    const int b   = blockIdx.y;
    const int tid = threadIdx.x;
    const int p   = blockIdx.x * 256 + tid;

    // Stage gt boxes for this batch into LDS; force invalid (sum==0) boxes to zeros.
    if (tid < GG) {
        float4 g = gt_boxes[b * GG + tid];
        float s = g.x + g.y + g.z + g.w;
        if (s == 0.0f) { g.x = 0.0f; g.y = 0.0f; g.z = 0.0f; g.w = 0.0f; }
        sgt[tid] = g;
        sag[tid] = (g.z - g.x) * (g.w - g.y);
    }
    __syncthreads();

    const float4 pb   = pred_boxes[b * PP + p];
    const float  sc   = pred_scores[b * PP + p];
    const bool   vp   = (pred_classes[b * PP + p] == 0);
    const float  ap   = (pb.z - pb.x) * (pb.w - pb.y);

    // Track max of inters/uni via cross-multiplication (all >= 0, uni > 0).
    float bi = 0.0f;   // best inters
    float bu = 1.0f;   // best uni
    #pragma unroll 8
    for (int g = 0; g < GG; ++g) {
        const float4 gb = sgt[g];          // uniform address -> LDS broadcast
        const float ixmin = fmaxf(gb.x, pb.x);
        const float iymin = fmaxf(gb.y, pb.y);
        const float ixmax = fminf(gb.z, pb.z);
        const float iymax = fminf(gb.w, pb.w);
        const float iw = fmaxf(ixmax - ixmin, 0.0f);
        const float ih = fmaxf(iymax - iymin, 0.0f);
        const float inter = iw * ih;
        const float uni = ap + sag[g] - inter;
        if (inter * bu > bi * uni) { bi = inter; bu = uni; }
    }

    float miou  = vp ? (bi / bu) : 0.0f;
    float mprob = vp ? sqrtf(sc + 1.0f) : 0.0f;

    // 64-lane wave max-reduce.
    #pragma unroll
    for (int off = 32; off >= 1; off >>= 1) {
        miou  = fmaxf(miou,  __shfl_xor(miou,  off, 64));
        mprob = fmaxf(mprob, __shfl_xor(mprob, off, 64));
    }

    // Non-negative floats: uint bit-pattern compare == float compare.
    if ((tid & 63) == 0) {
        atomicMax((unsigned int*)&out[b],      __float_as_uint(mprob));
        atomicMax((unsigned int*)&out[BB + b], __float_as_uint(miou));
    }
}

extern "C" void kernel_launch(void* const* d_in, const int* in_sizes, int n_in,
                              void* d_out, int out_size, void* d_ws, size_t ws_size,
                              hipStream_t stream) {
    const float4* pred_boxes   = (const float4*)d_in[0];
    const float*  pred_scores  = (const float*)d_in[1];
    const int*    pred_classes = (const int*)d_in[2];
    const float4* gt_boxes     = (const float4*)d_in[3];
    float* out = (float*)d_out;

    // Zero the 64 output accumulators (atomicMax targets) each call.
    hipMemsetAsync(out, 0, 2 * BB * sizeof(float), stream);

    dim3 grid(PP / 256, BB);
    dim3 block(256);
    MaxExtractor_kernel<<<grid, block, 0, stream>>>(
        pred_boxes, pred_scores, pred_classes, gt_boxes, out);
}

// Round 2
// 16.156 us; speedup vs baseline: 1.6798x; 1.6798x over previous
//
#include <hip/hip_runtime.h>

#define BB 32
#define PP 2048
#define GG 128
#define NT 1024

__global__ __launch_bounds__(NT) void MaxExtractor_kernel(
    const float4* __restrict__ pred_boxes,   // [B*P]
    const float*  __restrict__ pred_scores,  // [B*P]
    const int*    __restrict__ pred_classes, // [B*P]
    const float4* __restrict__ gt_boxes,     // [B*G]
    float*        __restrict__ out)          // [2*B]: [0..B)=max_prob, [B..2B)=max_iou
{
    __shared__ float4 spb[PP];        // compacted valid pred boxes (worst case all valid)
    __shared__ float4 sgt[GG + 8];    // compacted + zero-padded gt boxes
    __shared__ float  sag[GG + 8];    // gt areas
    __shared__ int    lcnt, gcnt;
    __shared__ float  r_iou[NT / 64], r_ms[NT / 64];

    const int b    = blockIdx.x;
    const int tid  = threadIdx.x;
    const int lane = tid & 63;

    if (tid == 0) { lcnt = 0; gcnt = 0; }
    __syncthreads();

    // ---- pass 1a: compact valid preds (class==0) into LDS; track max score ----
    float ms = -1.0f;
    #pragma unroll
    for (int i = tid; i < PP; i += NT) {
        const float4 box = pred_boxes[b * PP + i];
        const float  sc  = pred_scores[b * PP + i];
        const bool   v   = (pred_classes[b * PP + i] == 0);
        if (v) ms = fmaxf(ms, sc);
        const unsigned long long mask = __ballot(v);
        int base = 0;
        if (lane == 0) base = atomicAdd(&lcnt, __popcll(mask));
        base = __shfl(base, 0, 64);
        if (v) {
            const int off = __popcll(mask & ((1ull << lane) - 1ull));
            spb[base + off] = box;
        }
    }

    // ---- pass 1b: compact valid gts (sum != 0) ----
    {
        bool v = false;
        float4 g4 = make_float4(0.f, 0.f, 0.f, 0.f);
        if (tid < GG) {
            g4 = gt_boxes[b * GG + tid];
            v = (g4.x + g4.y + g4.z + g4.w) != 0.0f;
        }
        const unsigned long long mask = __ballot(v);
        int base = 0;
        if (lane == 0) base = atomicAdd(&gcnt, __popcll(mask));
        base = __shfl(base, 0, 64);
        if (v) {
            const int off = __popcll(mask & ((1ull << lane) - 1ull));
            sgt[base + off] = g4;
            sag[base + off] = (g4.z - g4.x) * (g4.w - g4.y);
        }
    }
    __syncthreads();

    const int Nv  = lcnt;
    const int Ngr = gcnt;
    const int Ng  = (Ngr + 7) & ~7;   // pad to multiple of 8 with zero boxes
    if (tid < 8 && (Ngr + tid) < Ng) {
        // zero box vs any pred: ixmin>=0, ixmax=0 -> iw==0 -> inter==0 (harmless)
        sgt[Ngr + tid] = make_float4(0.f, 0.f, 0.f, 0.f);
        sag[Ngr + tid] = 0.0f;
    }
    __syncthreads();

    // ---- pass 2: each pred handled by 2 threads (gt range split); wave-uniform g ----
    const int half = tid >> 9;                 // waves 0-7: half 0, waves 8-15: half 1
    const int g0 = half ? (Ng >> 1) : 0;
    const int g1 = half ? Ng : (Ng >> 1);
    float bi = 0.0f;   // best inters
    float bu = 1.0f;   // best uni   (track max inters/uni by cross-multiplication)
    for (int p = (tid & 511); p < Nv; p += 512) {
        const float4 pb = spb[p];
        const float  ap = (pb.z - pb.x) * (pb.w - pb.y);
        #pragma unroll 4
        for (int g = g0; g < g1; ++g) {
            const float4 gb = sgt[g];          // uniform addr -> LDS broadcast
            const float ixmin = fmaxf(gb.x, pb.x);
            const float iymin = fmaxf(gb.y, pb.y);
            const float ixmax = fminf(gb.z, pb.z);
            const float iymax = fminf(gb.w, pb.w);
            const float iw = fmaxf(ixmax - ixmin, 0.0f);
            const float ih = fmaxf(iymax - iymin, 0.0f);
            const float inter = iw * ih;
            const float uni = ap + sag[g] - inter;
            if (inter * bu > bi * uni) { bi = inter; bu = uni; }
        }
    }
    float miou = bi / bu;

    // ---- block max reduction ----
    #pragma unroll
    for (int off = 32; off >= 1; off >>= 1) {
        miou = fmaxf(miou, __shfl_xor(miou, off, 64));
        ms   = fmaxf(ms,   __shfl_xor(ms,   off, 64));
    }
    if (lane == 0) { r_iou[tid >> 6] = miou; r_ms[tid >> 6] = ms; }
    __syncthreads();
    if (tid == 0) {
        float mi = r_iou[0], mx = r_ms[0];
        #pragma unroll
        for (int w = 1; w < NT / 64; ++w) {
            mi = fmaxf(mi, r_iou[w]);
            mx = fmaxf(mx, r_ms[w]);
        }
        // no valid preds: mx=-1 -> sqrt(0)=0, mi=0 -> matches reference exactly
        out[b]      = sqrtf(mx + 1.0f);
        out[BB + b] = mi;
    }
}

extern "C" void kernel_launch(void* const* d_in, const int* in_sizes, int n_in,
                              void* d_out, int out_size, void* d_ws, size_t ws_size,
                              hipStream_t stream) {
    const float4* pred_boxes   = (const float4*)d_in[0];
    const float*  pred_scores  = (const float*)d_in[1];
    const int*    pred_classes = (const int*)d_in[2];
    const float4* gt_boxes     = (const float4*)d_in[3];
    float* out = (float*)d_out;

    MaxExtractor_kernel<<<dim3(BB), dim3(NT), 0, stream>>>(
        pred_boxes, pred_scores, pred_classes, gt_boxes, out);
}